// Round 4
// baseline (253.459 us; speedup 1.0000x reference)
//
#include <hip/hip_runtime.h>

#define DD 16
#define BB 8
#define NN 2048
#define WMAX 2.0f

typedef float vfloat4 __attribute__((ext_vector_type(4)));

// ---------------------------------------------------------------------------
// Main kernel: each thread owns one (e, o4) column group.
//   1. Hoist all 16 dmap[d,e,o4] lines into registers (nontemporal: dmap is
//      single-use streaming data, keep it out of L2/L3).
//   2. Accumulate over d for b in two halves of 4 (keeps live acc regs at 32
//      while dmap stays resident; total ~110 VGPR under the 128 cap from
//      __launch_bounds__(256,4)).
//   3. Epilogue per b: dW = accp*A_p*(Xpost*relu(u_pot)) - accd*A_d*relu(u_dep)
//      out_W = W (pre-update copy), out_Wnew = clip(W+dW, 0, WMAX),
//      both stored nontemporal (never re-read).
// e is wave-uniform (blockIdx only) -> coefficient loads scalarize to s_load.
// ---------------------------------------------------------------------------
__global__ __launch_bounds__(256, 4) void clopath_main(
    const float* __restrict__ Xd,        // (D,B,N)
    const float* __restrict__ Xpost,     // (B,N)
    const float* __restrict__ xbar_pre,  // (D,B,N)
    const float* __restrict__ u_pot,     // (B,N)
    const float* __restrict__ u_dep,     // (B,N)
    const float* __restrict__ W,         // (B,N,N)
    const float* __restrict__ A_p,       // (N,N)
    const float* __restrict__ A_d,       // (N,N)
    const float* __restrict__ dmap,      // (D,N,N)
    float* __restrict__ out_W,           // (B,N,N)  pre-update copy
    float* __restrict__ out_Wnew)        // (B,N,N)
{
    // blocks_per_row = (N/4)/256 = 2
    const int e = blockIdx.x >> 1;                                   // uniform
    const int o = ((((int)blockIdx.x & 1) << 8) | (int)threadIdx.x) << 2;
    const size_t eo = (size_t)e * NN + o;

    // All 16 dmap lines, held in registers for both b-halves.
    vfloat4 dm[DD];
#pragma unroll
    for (int d = 0; d < DD; ++d)
        dm[d] = __builtin_nontemporal_load(
            reinterpret_cast<const vfloat4*>(dmap + (size_t)d * NN * NN + eo));

    const vfloat4 ap = *reinterpret_cast<const vfloat4*>(A_p + eo);
    const vfloat4 ad = *reinterpret_cast<const vfloat4*>(A_d + eo);

#pragma unroll
    for (int bh = 0; bh < 2; ++bh) {
        vfloat4 accp[4], accd[4];
#pragma unroll
        for (int bi = 0; bi < 4; ++bi) {
            accp[bi] = (vfloat4)(0.f);
            accd[bi] = (vfloat4)(0.f);
        }

#pragma unroll
        for (int d = 0; d < DD; ++d) {
#pragma unroll
            for (int bi = 0; bi < 4; ++bi) {
                const int b = bh * 4 + bi;
                const float xb = xbar_pre[(d * BB + b) * NN + e];  // s_load
                const float xs = Xd[(d * BB + b) * NN + e];        // s_load
                accp[bi].x = fmaf(xb, dm[d].x, accp[bi].x);
                accp[bi].y = fmaf(xb, dm[d].y, accp[bi].y);
                accp[bi].z = fmaf(xb, dm[d].z, accp[bi].z);
                accp[bi].w = fmaf(xb, dm[d].w, accp[bi].w);
                accd[bi].x = fmaf(xs, dm[d].x, accd[bi].x);
                accd[bi].y = fmaf(xs, dm[d].y, accd[bi].y);
                accd[bi].z = fmaf(xs, dm[d].z, accd[bi].z);
                accd[bi].w = fmaf(xs, dm[d].w, accd[bi].w);
            }
        }

#pragma unroll
        for (int bi = 0; bi < 4; ++bi) {
            const int b = bh * 4 + bi;
            const int bo = b * NN + o;
            const vfloat4 xp = *reinterpret_cast<const vfloat4*>(Xpost + bo);
            const vfloat4 up = *reinterpret_cast<const vfloat4*>(u_pot + bo);
            const vfloat4 ud = *reinterpret_cast<const vfloat4*>(u_dep + bo);

            const size_t widx = (size_t)b * NN * NN + eo;
            const vfloat4 w4 = *reinterpret_cast<const vfloat4*>(W + widx);

            vfloat4 wn;
#define COMP(c)                                                                \
            {                                                                  \
                const float gp = xp.c * fmaxf(up.c, 0.f);                      \
                const float gd = fmaxf(ud.c, 0.f);                             \
                const float dw =                                               \
                    accp[bi].c * ap.c * gp - accd[bi].c * ad.c * gd;           \
                wn.c = fminf(fmaxf(w4.c + dw, 0.f), WMAX);                     \
            }
            COMP(x) COMP(y) COMP(z) COMP(w)
#undef COMP

            __builtin_nontemporal_store(
                w4, reinterpret_cast<vfloat4*>(out_W + widx));
            __builtin_nontemporal_store(
                wn, reinterpret_cast<vfloat4*>(out_Wnew + widx));
        }
    }
}

// ---------------------------------------------------------------------------
// Trace-filter kernel: xbar_pre_new, u_pot_new, u_dep_new (all tiny).
// ---------------------------------------------------------------------------
__global__ __launch_bounds__(256) void clopath_traces(
    const float* __restrict__ Xd,        // (D,B,N)
    const float* __restrict__ Vpost,     // (B,N)
    const float* __restrict__ xbar_pre,  // (D,B,N)
    const float* __restrict__ u_pot,     // (B,N)
    const float* __restrict__ u_dep,     // (B,N)
    float* __restrict__ out_xbar,        // (D,B,N)
    float* __restrict__ out_upot,        // (B,N)
    float* __restrict__ out_udep)        // (B,N)
{
    const int NXB = DD * BB * NN;  // 262144
    const int NU  = BB * NN;       // 16384
    int i = ((int)blockIdx.x * 256 + (int)threadIdx.x) * 4;
    if (i < NXB) {
        const vfloat4 xb = *reinterpret_cast<const vfloat4*>(xbar_pre + i);
        const vfloat4 xs = *reinterpret_cast<const vfloat4*>(Xd + i);
        vfloat4 r = 0.95f * xb + 0.05f * xs;
        *reinterpret_cast<vfloat4*>(out_xbar + i) = r;
    } else {
        int j = i - NXB;
        if (j < NU) {
            const vfloat4 u = *reinterpret_cast<const vfloat4*>(u_pot + j);
            const vfloat4 v = *reinterpret_cast<const vfloat4*>(Vpost + j);
            vfloat4 r = 0.9f * u + 0.1f * v;
            *reinterpret_cast<vfloat4*>(out_upot + j) = r;
        } else {
            j -= NU;
            if (j < NU) {
                const vfloat4 u = *reinterpret_cast<const vfloat4*>(u_dep + j);
                const vfloat4 v = *reinterpret_cast<const vfloat4*>(Vpost + j);
                vfloat4 r = 0.8f * u + 0.2f * v;
                *reinterpret_cast<vfloat4*>(out_udep + j) = r;
            }
        }
    }
}

extern "C" void kernel_launch(void* const* d_in, const int* in_sizes, int n_in,
                              void* d_out, int out_size, void* d_ws, size_t ws_size,
                              hipStream_t stream) {
    const float* Xd       = (const float*)d_in[0];
    const float* Xpost    = (const float*)d_in[1];
    const float* Vpost    = (const float*)d_in[2];
    const float* xbar_pre = (const float*)d_in[3];
    const float* u_pot    = (const float*)d_in[4];
    const float* u_dep    = (const float*)d_in[5];
    const float* W        = (const float*)d_in[6];
    const float* A_p      = (const float*)d_in[7];
    const float* A_d      = (const float*)d_in[8];
    const float* dmap     = (const float*)d_in[9];

    float* out = (float*)d_out;
    const size_t BNN = (size_t)BB * NN * NN;      // 33554432
    float* out_W    = out;                        // W pre-update copy
    float* out_Wnew = out + BNN;                  // W_new
    float* out_xbar = out + 2 * BNN;              // (D,B,N)
    float* out_upot = out_xbar + (size_t)DD * BB * NN;
    float* out_udep = out_upot + (size_t)BB * NN;

    // Main: N rows, 2 blocks of 256 threads per row (each thread = 4 o's).
    dim3 grid_main(NN * 2);
    clopath_main<<<grid_main, 256, 0, stream>>>(
        Xd, Xpost, xbar_pre, u_pot, u_dep, W, A_p, A_d, dmap,
        out_W, out_Wnew);

    // Traces: (262144 + 16384 + 16384)/4 = 73728 threads -> 288 blocks.
    clopath_traces<<<288, 256, 0, stream>>>(
        Xd, Vpost, xbar_pre, u_pot, u_dep,
        out_xbar, out_upot, out_udep);
}

// Round 5
// 247.433 us; speedup vs baseline: 1.0244x; 1.0244x over previous
//
#include <hip/hip_runtime.h>

#define DD 16
#define BB 8
#define NN 2048
#define WMAX 2.0f

typedef float vfloat4 __attribute__((ext_vector_type(4)));

// ---------------------------------------------------------------------------
// Prep kernel: transpose coefficients into per-e contiguous blocks.
//   coefT[e][d][0][b] = xbar_pre[d][b][e]
//   coefT[e][d][1][b] = Xd[d][b][e]
// Layout stride: e*256 + d*16 + s*8 + b  (2 KB per e, 64B-aligned per d).
// 2 MB total -> lives in L2 for the main kernel's scalar loads.
// ---------------------------------------------------------------------------
__global__ __launch_bounds__(256) void clopath_prep(
    const float* __restrict__ Xd,        // (D,B,N)
    const float* __restrict__ xbar_pre,  // (D,B,N)
    float* __restrict__ coefT)           // (N, D, 2, B)
{
    // grid: (D*B) * (N/256) = 128 * 8 = 1024 blocks
    const int blk = (int)blockIdx.x;
    const int echunk = blk & 7;          // N/256 = 8 chunks
    const int db = blk >> 3;             // db = d*BB + b
    const int d = db >> 3;
    const int b = db & 7;
    const int e = echunk * 256 + (int)threadIdx.x;

    const float xb = xbar_pre[(size_t)db * NN + e];  // coalesced over e
    const float xs = Xd[(size_t)db * NN + e];        // coalesced over e
    coefT[(size_t)e * 256 + d * 16 + b]     = xb;    // scattered, L2-absorbed
    coefT[(size_t)e * 256 + d * 16 + 8 + b] = xs;
}

// ---------------------------------------------------------------------------
// Main kernel (R2 structure, plain cached loads/stores):
//   d-outer: load dmap[d,e,o4] once, accumulate all 8 b with wave-uniform
//   coefficients from coefT (contiguous -> wide s_load_dwordx16).
// Epilogue per b: dW = accp*A_p*(Xpost*relu(u_pot)) - accd*A_d*relu(u_dep);
//   out_W = W (pre-update copy); out_Wnew = clip(W+dW, 0, WMAX).
// ---------------------------------------------------------------------------
__global__ __launch_bounds__(256, 4) void clopath_main(
    const float* __restrict__ coefT,     // (N,D,2,B)
    const float* __restrict__ Xpost,     // (B,N)
    const float* __restrict__ u_pot,     // (B,N)
    const float* __restrict__ u_dep,     // (B,N)
    const float* __restrict__ W,         // (B,N,N)
    const float* __restrict__ A_p,       // (N,N)
    const float* __restrict__ A_d,       // (N,N)
    const float* __restrict__ dmap,      // (D,N,N)
    float* __restrict__ out_W,           // (B,N,N)  pre-update copy
    float* __restrict__ out_Wnew)        // (B,N,N)
{
    // blocks_per_row = (N/4)/256 = 2
    const int e = blockIdx.x >> 1;                                   // uniform
    const int o = ((((int)blockIdx.x & 1) << 8) | (int)threadIdx.x) << 2;
    const size_t eo = (size_t)e * NN + o;
    const float* __restrict__ ce = coefT + (size_t)e * 256;          // uniform

    vfloat4 accp[BB], accd[BB];
#pragma unroll
    for (int b = 0; b < BB; ++b) {
        accp[b] = (vfloat4)(0.f);
        accd[b] = (vfloat4)(0.f);
    }

#pragma unroll
    for (int d = 0; d < DD; ++d) {
        const vfloat4 dmv =
            *reinterpret_cast<const vfloat4*>(dmap + (size_t)d * NN * NN + eo);
#pragma unroll
        for (int b = 0; b < BB; ++b) {
            const float xb = ce[d * 16 + b];      // s_load, contiguous
            const float xs = ce[d * 16 + 8 + b];  // s_load, contiguous
            accp[b].x = fmaf(xb, dmv.x, accp[b].x);
            accp[b].y = fmaf(xb, dmv.y, accp[b].y);
            accp[b].z = fmaf(xb, dmv.z, accp[b].z);
            accp[b].w = fmaf(xb, dmv.w, accp[b].w);
            accd[b].x = fmaf(xs, dmv.x, accd[b].x);
            accd[b].y = fmaf(xs, dmv.y, accd[b].y);
            accd[b].z = fmaf(xs, dmv.z, accd[b].z);
            accd[b].w = fmaf(xs, dmv.w, accd[b].w);
        }
    }

    const vfloat4 ap = *reinterpret_cast<const vfloat4*>(A_p + eo);
    const vfloat4 ad = *reinterpret_cast<const vfloat4*>(A_d + eo);

#pragma unroll
    for (int b = 0; b < BB; ++b) {
        const int bo = b * NN + o;
        const vfloat4 xp = *reinterpret_cast<const vfloat4*>(Xpost + bo);
        const vfloat4 up = *reinterpret_cast<const vfloat4*>(u_pot + bo);
        const vfloat4 ud = *reinterpret_cast<const vfloat4*>(u_dep + bo);

        const size_t widx = (size_t)b * NN * NN + eo;
        const vfloat4 w4 = *reinterpret_cast<const vfloat4*>(W + widx);

        vfloat4 wn;
#define COMP(c)                                                              \
        {                                                                    \
            const float gp = xp.c * fmaxf(up.c, 0.f);                        \
            const float gd = fmaxf(ud.c, 0.f);                               \
            const float dw = accp[b].c * ap.c * gp - accd[b].c * ad.c * gd;  \
            wn.c = fminf(fmaxf(w4.c + dw, 0.f), WMAX);                       \
        }
        COMP(x) COMP(y) COMP(z) COMP(w)
#undef COMP

        *reinterpret_cast<vfloat4*>(out_W + widx)    = w4;
        *reinterpret_cast<vfloat4*>(out_Wnew + widx) = wn;
    }
}

// ---------------------------------------------------------------------------
// Trace-filter kernel: xbar_pre_new, u_pot_new, u_dep_new (all tiny).
// ---------------------------------------------------------------------------
__global__ __launch_bounds__(256) void clopath_traces(
    const float* __restrict__ Xd,        // (D,B,N)
    const float* __restrict__ Vpost,     // (B,N)
    const float* __restrict__ xbar_pre,  // (D,B,N)
    const float* __restrict__ u_pot,     // (B,N)
    const float* __restrict__ u_dep,     // (B,N)
    float* __restrict__ out_xbar,        // (D,B,N)
    float* __restrict__ out_upot,        // (B,N)
    float* __restrict__ out_udep)        // (B,N)
{
    const int NXB = DD * BB * NN;  // 262144
    const int NU  = BB * NN;       // 16384
    int i = ((int)blockIdx.x * 256 + (int)threadIdx.x) * 4;
    if (i < NXB) {
        const vfloat4 xb = *reinterpret_cast<const vfloat4*>(xbar_pre + i);
        const vfloat4 xs = *reinterpret_cast<const vfloat4*>(Xd + i);
        vfloat4 r = 0.95f * xb + 0.05f * xs;
        *reinterpret_cast<vfloat4*>(out_xbar + i) = r;
    } else {
        int j = i - NXB;
        if (j < NU) {
            const vfloat4 u = *reinterpret_cast<const vfloat4*>(u_pot + j);
            const vfloat4 v = *reinterpret_cast<const vfloat4*>(Vpost + j);
            vfloat4 r = 0.9f * u + 0.1f * v;
            *reinterpret_cast<vfloat4*>(out_upot + j) = r;
        } else {
            j -= NU;
            if (j < NU) {
                const vfloat4 u = *reinterpret_cast<const vfloat4*>(u_dep + j);
                const vfloat4 v = *reinterpret_cast<const vfloat4*>(Vpost + j);
                vfloat4 r = 0.8f * u + 0.2f * v;
                *reinterpret_cast<vfloat4*>(out_udep + j) = r;
            }
        }
    }
}

extern "C" void kernel_launch(void* const* d_in, const int* in_sizes, int n_in,
                              void* d_out, int out_size, void* d_ws, size_t ws_size,
                              hipStream_t stream) {
    const float* Xd       = (const float*)d_in[0];
    const float* Xpost    = (const float*)d_in[1];
    const float* Vpost    = (const float*)d_in[2];
    const float* xbar_pre = (const float*)d_in[3];
    const float* u_pot    = (const float*)d_in[4];
    const float* u_dep    = (const float*)d_in[5];
    const float* W        = (const float*)d_in[6];
    const float* A_p      = (const float*)d_in[7];
    const float* A_d      = (const float*)d_in[8];
    const float* dmap     = (const float*)d_in[9];

    float* out = (float*)d_out;
    const size_t BNN = (size_t)BB * NN * NN;      // 33554432
    float* out_W    = out;                        // W pre-update copy
    float* out_Wnew = out + BNN;                  // W_new
    float* out_xbar = out + 2 * BNN;              // (D,B,N)
    float* out_upot = out_xbar + (size_t)DD * BB * NN;
    float* out_udep = out_upot + (size_t)BB * NN;

    float* coefT = (float*)d_ws;                  // (N,D,2,B) = 2 MB

    // Prep: transpose coefficients (1024 blocks x 256).
    clopath_prep<<<1024, 256, 0, stream>>>(Xd, xbar_pre, coefT);

    // Main: N rows, 2 blocks of 256 threads per row (each thread = 4 o's).
    dim3 grid_main(NN * 2);
    clopath_main<<<grid_main, 256, 0, stream>>>(
        coefT, Xpost, u_pot, u_dep, W, A_p, A_d, dmap,
        out_W, out_Wnew);

    // Traces: (262144 + 16384 + 16384)/4 = 73728 threads -> 288 blocks.
    clopath_traces<<<288, 256, 0, stream>>>(
        Xd, Vpost, xbar_pre, u_pot, u_dep,
        out_xbar, out_upot, out_udep);
}